// Round 20
// baseline (261.471 us; speedup 1.0000x reference)
//
#include <hip/hip_runtime.h>
#include <math.h>

#define N_NODES 50000
#define N_EDGES 800000
#define C 64
#define H 4
#define D 16
#define HC 256
#define BN_EPS 1e-5f
#define NCHUNK 49            // ceil(N_NODES / 1024)
#define LOG2E 1.44269504f
#define FBLOCKS 4096
#define PROWS 64             // rows per proj2 block
#define PCH 32               // rows per staged chunk
#define PBLK 782             // ceil(N_NODES / PROWS)
#define FILLBLK 3125         // N_EDGES / 256
#define UBIAS 4.0f           // uniform logit bias: wt=exp2(u-4) keeps f16 accums in range

typedef _Float16 h2 __attribute__((ext_vector_type(2)));
typedef __fp16 fp16x2 __attribute__((ext_vector_type(2)));

__device__ __forceinline__ float dot2h(h2 a, h2 b, float c) {
#if __has_builtin(__builtin_amdgcn_fdot2)
    return __builtin_amdgcn_fdot2(a, b, c, false);
#else
    return c + (float)a.x * (float)b.x + (float)a.y * (float)b.y;
#endif
}

__device__ __forceinline__ h2 pkrtz(float lo, float hi) {
    fp16x2 r = __builtin_amdgcn_cvt_pkrtz(lo, hi);
    return __builtin_bit_cast(h2, r);
}

__device__ __forceinline__ unsigned int packh2(float lo, float hi) {
    return __builtin_bit_cast(unsigned int, pkrtz(lo, hi));
}

__device__ __forceinline__ h2 ash2(unsigned int u) {
    return __builtin_bit_cast(h2, u);
}

__device__ __forceinline__ h2 absh2(h2 v) {
    unsigned int u = __builtin_bit_cast(unsigned int, v) & 0x7FFF7FFFu;
    return __builtin_bit_cast(h2, u);
}

__device__ __forceinline__ float4 h4cvt(uint2 u) {
    h2 a = ash2(u.x);
    h2 b = ash2(u.y);
    return make_float4((float)a.x, (float)a.y, (float)b.x, (float)b.y);
}

// 16-lane (DPP row) rotate-add; after ror8,4,2,1 every lane holds its 16-group sum.
template <int CTRL>
__device__ __forceinline__ float ror_add(float x) {
    int y = __builtin_amdgcn_update_dpp(0, __float_as_int(x), CTRL, 0xF, 0xF, true);
    return x + __int_as_float(y);
}
__device__ __forceinline__ float row_reduce(float u) {
    u = ror_add<0x128>(u);
    u = ror_add<0x124>(u);
    u = ror_add<0x122>(u);
    u = ror_add<0x121>(u);
    return u;
}

__device__ __forceinline__ float fast_exp2(float x) {
    float r;
    asm("v_exp_f32 %0, %1" : "=v"(r) : "v"(x));
    return r;
}

// leaky_relu(z, 0.2) == 0.6*z + 0.4*|z| (f32 scalar, used in self-loop only)
__device__ __forceinline__ float lrelu(float z) {
    return fmaf(0.4f, fabsf(z), 0.6f * z);
}

// packed f16 leaky_relu over 2 channels
__device__ __forceinline__ h2 lrelu_pk(h2 z) {
    const h2 k06 = {(_Float16)0.6f, (_Float16)0.6f};
    const h2 k04 = {(_Float16)0.4f, (_Float16)0.4f};
    return z * k06 + absh2(z) * k04;
}

// ---------------- per-dst edge counts ----------------
__global__ void __launch_bounds__(256) cnt_kernel(const int* __restrict__ dst,
                                                  int* __restrict__ cnt) {
    int e = blockIdx.x * 256 + threadIdx.x;
    if (e < N_EDGES) atomicAdd(&cnt[dst[e]], 1);
}

// ---------------- scan A: per-chunk sums ----------------
__global__ void __launch_bounds__(256) scanA_kernel(const int* __restrict__ cnt,
                                                    int* __restrict__ part) {
    __shared__ int red[256];
    int b = blockIdx.x, tid = threadIdx.x;
    int base = b * 1024 + tid;
    int s = 0;
#pragma unroll
    for (int q = 0; q < 4; ++q) {
        int g = base + q * 256;
        s += (g < N_NODES) ? cnt[g] : 0;
    }
    red[tid] = s;
    __syncthreads();
    if (tid < 128) red[tid] += red[tid + 128];
    __syncthreads();
    if (tid < 64) {
        int v = red[tid] + red[tid + 64];
#pragma unroll
        for (int o = 32; o > 0; o >>= 1) v += __shfl_xor(v, o, 64);
        if (tid == 0) part[b] = v;
    }
}

// ---------------- scan C: per-chunk local scan; chunk base computed in-block ----------------
__global__ void scanC_kernel(const int* __restrict__ cnt, const int* __restrict__ part,
                             int* __restrict__ off) {
    __shared__ int wsum[16];
    __shared__ int base_s;
    int b = blockIdx.x, tid = threadIdx.x;
    int lane = tid & 63, w = tid >> 6;
    int i = b * 1024 + tid;
    int v = (i < N_NODES) ? cnt[i] : 0;
    int xv = v;
    for (int o = 1; o < 64; o <<= 1) {
        int t = __shfl_up(xv, o, 64);
        if (lane >= o) xv += t;
    }
    if (lane == 63) wsum[w] = xv;
    __syncthreads();
    if (tid < 64) {
        int pv = (tid < NCHUNK) ? part[tid] : 0;
        int px = pv;
        for (int o = 1; o < 64; o <<= 1) {
            int t = __shfl_up(px, o, 64);
            if (lane >= o) px += t;
        }
        if (tid == b) base_s = px - pv;
        int y = (tid < 16) ? wsum[tid] : 0;
        for (int o = 1; o < 16; o <<= 1) {
            int t = __shfl_up(y, o, 64);
            if (tid >= o) y += t;
        }
        if (tid < 16) wsum[tid] = y;
    }
    __syncthreads();
    int prefix = base_s + ((w > 0) ? wsum[w - 1] : 0);
    if (i < N_NODES) off[i + 1] = prefix + xv;
    if (b == 0 && tid == 0) off[0] = 0;
}

// ---------------- K4: proj2 (LDS row-broadcast GEMM, f32 in-staging cvt) UNION csr_fill ----
__global__ void __launch_bounds__(256) k4_kernel(const float* __restrict__ x,
                                                 const float* __restrict__ Wl,
                                                 const float* __restrict__ Wr,
                                                 unsigned short* __restrict__ xlh,
                                                 unsigned short* __restrict__ xrh,
                                                 const int* __restrict__ src,
                                                 const int* __restrict__ dst,
                                                 const float* __restrict__ ea,
                                                 const int* __restrict__ csr_off,
                                                 int* __restrict__ fill,
                                                 int* __restrict__ csr_src,
                                                 unsigned int* __restrict__ ea16) {
    __shared__ unsigned int lds[2][PCH * 32];
    int bid = blockIdx.x;
    int tid = threadIdx.x;

    if (bid >= PBLK) {
        // ---------------- csr_fill part ----------------
        int e = (bid - PBLK) * 256 + tid;
        if (e >= N_EDGES) return;
        int d = dst[e];
        int pos = csr_off[d] + atomicAdd(&fill[d], 1);
        csr_src[pos] = src[e];
        const float4* er = (const float4*)(ea + ((size_t)e << 4));
        float4 f0 = er[0], f1 = er[1], f2 = er[2], f3 = er[3];
        uint4 u0, u1;
        u0.x = packh2(f0.x, f0.y); u0.y = packh2(f0.z, f0.w);
        u0.z = packh2(f1.x, f1.y); u0.w = packh2(f1.z, f1.w);
        u1.x = packh2(f2.x, f2.y); u1.y = packh2(f2.z, f2.w);
        u1.z = packh2(f3.x, f3.y); u1.w = packh2(f3.z, f3.w);
        uint4* dp = (uint4*)(ea16 + ((size_t)pos << 3));
        dp[0] = u0;
        dp[1] = u1;
        return;
    }

    // ---------------- proj2 part ----------------
    int lane = tid & 63;
    int w = tid >> 6;
    int c0 = w * 128 + 2 * lane;              // first col of the pair
    const float* W = (c0 < HC) ? (Wl + c0) : (Wr + (c0 - HC));
    unsigned short* dp = (c0 < HC) ? (xlh + c0) : (xrh + (c0 - HC));

    h2 wa[32], wb[32];
#pragma unroll
    for (int m = 0; m < 32; ++m) {
        float2 lo = *(const float2*)(W + (size_t)(2 * m) * HC);
        float2 hi = *(const float2*)(W + (size_t)(2 * m + 1) * HC);
        wa[m] = pkrtz(lo.x, hi.x);
        wb[m] = pkrtz(lo.y, hi.y);
    }

    int row0 = bid * PROWS;
    if (row0 >= N_NODES) return;
    int nch = (N_NODES - row0 + PCH - 1) / PCH;
    if (nch > 2) nch = 2;

    auto GLOAD = [&](int base) -> uint4 {
        int r = base + (tid >> 3);
        if (r >= N_NODES) r = N_NODES - 1;
        const float4* xp = (const float4*)(x + ((size_t)r << 6)) + ((tid & 7) << 1);
        float4 a = xp[0], b = xp[1];
        uint4 u;
        u.x = packh2(a.x, a.y); u.y = packh2(a.z, a.w);
        u.z = packh2(b.x, b.y); u.w = packh2(b.z, b.w);
        return u;
    };

    uint4 reg = GLOAD(row0);
    for (int c = 0; c < nch; ++c) {
        ((uint4*)lds[c & 1])[tid] = reg;
        __syncthreads();
        if (c + 1 < nch) reg = GLOAD(row0 + (c + 1) * PCH);
        const unsigned int* L = lds[c & 1];
        int rbase = row0 + c * PCH;
        int rcnt = N_NODES - rbase;
        if (rcnt > PCH) rcnt = PCH;
        for (int r = 0; r < rcnt; ++r) {
            const uint4* rp = (const uint4*)(L + r * 32);
            float a0 = 0.f, a1 = 0.f;
#pragma unroll
            for (int q = 0; q < 8; ++q) {
                uint4 v = rp[q];
                a0 = dot2h(ash2(v.x), wa[4 * q + 0], a0);
                a1 = dot2h(ash2(v.x), wb[4 * q + 0], a1);
                a0 = dot2h(ash2(v.y), wa[4 * q + 1], a0);
                a1 = dot2h(ash2(v.y), wb[4 * q + 1], a1);
                a0 = dot2h(ash2(v.z), wa[4 * q + 2], a0);
                a1 = dot2h(ash2(v.z), wb[4 * q + 2], a1);
                a0 = dot2h(ash2(v.w), wa[4 * q + 3], a0);
                a1 = dot2h(ash2(v.w), wb[4 * q + 3], a1);
            }
            *(unsigned int*)(dp + (size_t)(rbase + r) * HC) = packh2(a0, a1);
        }
        __syncthreads();
    }
}

// ---------------- fused GATv2: one wave per node, unroll-3 clamp-free main loop ----------
__global__ void __launch_bounds__(256) fused_kernel(const int* __restrict__ csr_off,
                                                    const int* __restrict__ csr_src,
                                                    const unsigned int* __restrict__ ea16,
                                                    const unsigned short* __restrict__ xlh,
                                                    const unsigned short* __restrict__ xrh,
                                                    const float* __restrict__ We,
                                                    const float* __restrict__ att,
                                                    const float* __restrict__ bias,
                                                    float* __restrict__ out) {
    int gtid = blockIdx.x * blockDim.x + threadIdx.x;
    int gw = gtid >> 6;
    int nw = (gridDim.x * blockDim.x) >> 6;
    int lane = threadIdx.x & 63;
    int c0 = lane & 15;
    int colbase = (lane >> 4) * C + c0 * 4;

    // per-lane W_e columns as packed f16 pairs
    h2 wh0[8], wh1[8], wh2[8], wh3[8];
#pragma unroll
    for (int k2 = 0; k2 < 8; ++k2) {
        float4 lo = *(const float4*)(We + (size_t)(2 * k2) * HC + colbase);
        float4 hi = *(const float4*)(We + (size_t)(2 * k2 + 1) * HC + colbase);
        wh0[k2].x = (_Float16)lo.x; wh0[k2].y = (_Float16)hi.x;
        wh1[k2].x = (_Float16)lo.y; wh1[k2].y = (_Float16)hi.y;
        wh2[k2].x = (_Float16)lo.z; wh2[k2].y = (_Float16)hi.z;
        wh3[k2].x = (_Float16)lo.w; wh3[k2].y = (_Float16)hi.w;
    }
    float4 av = *(const float4*)(att + colbase);
    av.x *= LOG2E; av.y *= LOG2E; av.z *= LOG2E; av.w *= LOG2E;   // log2 domain
    h2 attp01 = pkrtz(av.x, av.y);
    h2 attp23 = pkrtz(av.z, av.w);
    float4 bv = *(const float4*)(bias + c0 * 4);                  // loop-invariant

    for (int iv = gw; iv < N_NODES; iv += nw) {
        int i = __builtin_amdgcn_readfirstlane(iv);
        int off = __builtin_amdgcn_readfirstlane(csr_off[i]);
        int deg = __builtin_amdgcn_readfirstlane(csr_off[i + 1]) - off;
        const int* ps = csr_src + off;
        const uint4* pe = (const uint4*)(ea16 + ((size_t)off << 3));

        uint2 xrtu = *(const uint2*)(xrh + ((size_t)i << 8) + colbase);
        h2 xrtp0 = ash2(xrtu.x);
        h2 xrtp1 = ash2(xrtu.y);

        float den = 0.f;
        h2 ap0 = {(_Float16)0.f, (_Float16)0.f};     // packed f16 aggregation (4 ch)
        h2 ap1 = ap0;
        float s0 = 0.f, s1 = 0.f, s2 = 0.f, s3 = 0.f;

        // process edge j using gathered row g (packed f16, 4 ch)
        auto body = [&](int j, uint2 g) {
            uint4 eA = pe[2 * j];
            uint4 eB = pe[2 * j + 1];
            float e0 = 0.f, e1 = 0.f, e2 = 0.f, e3 = 0.f;
            h2 q;
            q = ash2(eA.x);
            e0 = dot2h(q, wh0[0], e0); e1 = dot2h(q, wh1[0], e1);
            e2 = dot2h(q, wh2[0], e2); e3 = dot2h(q, wh3[0], e3);
            q = ash2(eA.y);
            e0 = dot2h(q, wh0[1], e0); e1 = dot2h(q, wh1[1], e1);
            e2 = dot2h(q, wh2[1], e2); e3 = dot2h(q, wh3[1], e3);
            q = ash2(eA.z);
            e0 = dot2h(q, wh0[2], e0); e1 = dot2h(q, wh1[2], e1);
            e2 = dot2h(q, wh2[2], e2); e3 = dot2h(q, wh3[2], e3);
            q = ash2(eA.w);
            e0 = dot2h(q, wh0[3], e0); e1 = dot2h(q, wh1[3], e1);
            e2 = dot2h(q, wh2[3], e2); e3 = dot2h(q, wh3[3], e3);
            q = ash2(eB.x);
            e0 = dot2h(q, wh0[4], e0); e1 = dot2h(q, wh1[4], e1);
            e2 = dot2h(q, wh2[4], e2); e3 = dot2h(q, wh3[4], e3);
            q = ash2(eB.y);
            e0 = dot2h(q, wh0[5], e0); e1 = dot2h(q, wh1[5], e1);
            e2 = dot2h(q, wh2[5], e2); e3 = dot2h(q, wh3[5], e3);
            q = ash2(eB.z);
            e0 = dot2h(q, wh0[6], e0); e1 = dot2h(q, wh1[6], e1);
            e2 = dot2h(q, wh2[6], e2); e3 = dot2h(q, wh3[6], e3);
            q = ash2(eB.w);
            e0 = dot2h(q, wh0[7], e0); e1 = dot2h(q, wh1[7], e1);
            e2 = dot2h(q, wh2[7], e2); e3 = dot2h(q, wh3[7], e3);

            s0 += e0; s1 += e1; s2 += e2; s3 += e3;

            h2 xs0 = ash2(g.x);
            h2 xs1 = ash2(g.y);
            h2 z0 = pkrtz(e0, e1) + xs0 + xrtp0;
            h2 z1 = pkrtz(e2, e3) + xs1 + xrtp1;
            float u = dot2h(lrelu_pk(z0), attp01, 0.f);
            u = dot2h(lrelu_pk(z1), attp23, u);
            u = row_reduce(u);

            float wt = fast_exp2(u - UBIAS);
            den += wt;
            h2 wtp = pkrtz(wt, wt);
            ap0 = xs0 * wtp + ap0;
            ap1 = xs1 * wtp + ap1;
        };

        auto gload = [&](int j) -> uint2 {
            int t = __builtin_amdgcn_readfirstlane(ps[j]);
            return *(const uint2*)(xlh + ((size_t)t << 8) + colbase);
        };

        // initial prefetch (clamped)
        uint2 g0 = make_uint2(0, 0), g1 = g0, g2 = g0;
        if (deg > 0) {
            g0 = gload(0);
            g1 = gload((deg > 1) ? 1 : 0);
            g2 = gload((deg > 2) ? 2 : 0);
        }

        int j = 0;
        // main loop: unroll-3, clamp-free (prefetch targets j+3..j+5 all < deg)
        for (; j + 6 <= deg; j += 3) {
            body(j, g0);     g0 = gload(j + 3);
            body(j + 1, g1); g1 = gload(j + 4);
            body(j + 2, g2); g2 = gload(j + 5);
        }
        // tail: rotating ring with clamps (<= 5 iterations)
        for (; j < deg; ++j) {
            int jn = (j + 3 < deg) ? (j + 3) : (deg - 1);
            uint2 g3 = gload(jn);
            body(j, g0);
            g0 = g1; g1 = g2; g2 = g3;
        }

        // ---- self loop: ee_self = mean(ee_j) by linearity (f32 path, once) ----
        uint2 xliu = *(const uint2*)(xlh + ((size_t)i << 8) + colbase);
        float4 xli = h4cvt(xliu);
        float4 xrt = h4cvt(xrtu);
        float dninv = 1.f / fmaxf((float)deg, 1.f);
        {
            float z0 = fmaf(s0, dninv, xli.x + xrt.x);
            float z1 = fmaf(s1, dninv, xli.y + xrt.y);
            float z2 = fmaf(s2, dninv, xli.z + xrt.z);
            float z3 = fmaf(s3, dninv, xli.w + xrt.w);
            float u = lrelu(z0) * av.x;
            u = fmaf(lrelu(z1), av.y, u);
            u = fmaf(lrelu(z2), av.z, u);
            u = fmaf(lrelu(z3), av.w, u);
            u = row_reduce(u);
            float wt = fast_exp2(u - UBIAS);
            den += wt;
            h2 wtp = pkrtz(wt, wt);
            ap0 = ash2(xliu.x) * wtp + ap0;
            ap1 = ash2(xliu.y) * wtp + ap1;
        }

        // ---- normalize, head mean, bias, store ----
        float inv = 1.f / den;
        float r0 = (float)ap0.x * inv, r1 = (float)ap0.y * inv;
        float r2 = (float)ap1.x * inv, r3 = (float)ap1.y * inv;
        r0 += __shfl_xor(r0, 16); r0 += __shfl_xor(r0, 32);
        r1 += __shfl_xor(r1, 16); r1 += __shfl_xor(r1, 32);
        r2 += __shfl_xor(r2, 16); r2 += __shfl_xor(r2, 32);
        r3 += __shfl_xor(r3, 16); r3 += __shfl_xor(r3, 32);
        if (lane < 16) {
            float4 o;
            o.x = fmaf(r0, 0.25f, bv.x);
            o.y = fmaf(r1, 0.25f, bv.y);
            o.z = fmaf(r2, 0.25f, bv.z);
            o.w = fmaf(r3, 0.25f, bv.w);
            *(float4*)(out + (size_t)i * C + c0 * 4) = o;
        }
    }
}

// ---------------- BN statistics (sum, sumsq per channel) ----------------
__global__ void __launch_bounds__(256) bn_stats_kernel(const float* __restrict__ out,
                                                       float* __restrict__ bn) {
    int tid = threadIdx.x;
    int c = tid & 63;
    int r0 = blockIdx.x * 256 + (tid >> 6);
    int rend = (blockIdx.x * 256 + 256 < N_NODES) ? blockIdx.x * 256 + 256 : N_NODES;
    float s = 0.f, s2 = 0.f;
    for (int r = r0; r < rend; r += 4) {
        float v = out[(size_t)r * C + c];
        s += v; s2 += v * v;
    }
    __shared__ float red[256], red2[256];
    red[tid] = s; red2[tid] = s2;
    __syncthreads();
    if (tid < 128) { red[tid] += red[tid + 128]; red2[tid] += red2[tid + 128]; }
    __syncthreads();
    if (tid < 64) {
        atomicAdd(&bn[c], red[tid] + red[tid + 64]);
        atomicAdd(&bn[64 + c], red2[tid] + red2[tid + 64]);
    }
}

// ---------------- BN normalize + residual + ReLU (in place on out) ----------------
__global__ void __launch_bounds__(256) final_kernel(const float* __restrict__ x,
                                                    const float* __restrict__ bn,
                                                    const float* __restrict__ gamma,
                                                    const float* __restrict__ beta,
                                                    float* __restrict__ out) {
    int idx = blockIdx.x * 256 + threadIdx.x;
    if (idx >= N_NODES * C) return;
    int c = idx & 63;
    float mu = bn[c] * (1.f / N_NODES);
    float var = bn[64 + c] * (1.f / N_NODES) - mu * mu;
    float o = out[idx];
    float y = gamma[c] * (o - mu) * rsqrtf(var + BN_EPS) + beta[c] + x[idx];
    out[idx] = fmaxf(y, 0.f);
}

extern "C" void kernel_launch(void* const* d_in, const int* in_sizes, int n_in,
                              void* d_out, int out_size, void* d_ws, size_t ws_size,
                              hipStream_t stream) {
    const float* x     = (const float*)d_in[0];
    const int*   ei    = (const int*)d_in[1];
    const float* ea    = (const float*)d_in[2];
    const float* W_l   = (const float*)d_in[3];
    const float* W_r   = (const float*)d_in[4];
    const float* W_e   = (const float*)d_in[5];
    const float* att   = (const float*)d_in[6];
    const float* bias  = (const float*)d_in[7];
    const float* gamma = (const float*)d_in[8];
    const float* beta  = (const float*)d_in[9];
    float* out = (float*)d_out;

    const int* src = ei;
    const int* dst = ei + N_EDGES;

    char* p = (char*)d_ws;
    float*          bn      = (float*)p;          p += 512;
    int*            cnt     = (int*)p;            p += (size_t)N_NODES * 4;
    int*            fill    = (int*)p;            p += (size_t)N_NODES * 4;
    int*            csr_off = (int*)p;            p += (size_t)(N_NODES + 4) * 4;
    int*            part    = (int*)p;            p += 256;
    int*            csr_src = (int*)p;            p += (size_t)N_EDGES * 4;
    unsigned int*   ea16    = (unsigned int*)p;   p += (size_t)N_EDGES * 32;
    unsigned short* xlh     = (unsigned short*)p; p += (size_t)N_NODES * HC * 2;
    unsigned short* xrh     = (unsigned short*)p; p += (size_t)N_NODES * HC * 2;

    // zero bn + cnt + fill (contiguous)
    hipMemsetAsync(bn, 0, 512 + 2 * (size_t)N_NODES * 4, stream);

    cnt_kernel<<<FILLBLK, 256, 0, stream>>>(dst, cnt);
    scanA_kernel<<<NCHUNK, 256, 0, stream>>>(cnt, part);
    scanC_kernel<<<NCHUNK, 1024, 0, stream>>>(cnt, part, csr_off);
    k4_kernel<<<PBLK + FILLBLK, 256, 0, stream>>>(x, W_l, W_r, xlh, xrh,
                                                  src, dst, ea, csr_off, fill,
                                                  csr_src, ea16);
    fused_kernel<<<FBLOCKS, 256, 0, stream>>>(csr_off, csr_src, ea16, xlh, xrh, W_e,
                                              att, bias, out);
    bn_stats_kernel<<<(N_NODES + 255) / 256, 256, 0, stream>>>(out, bn);
    final_kernel<<<(N_NODES * C) / 256, 256, 0, stream>>>(x, bn, gamma, beta, out);
}

// Round 21
// 257.146 us; speedup vs baseline: 1.0168x; 1.0168x over previous
//
#include <hip/hip_runtime.h>
#include <math.h>

#define N_NODES 50000
#define N_EDGES 800000
#define C 64
#define H 4
#define D 16
#define HC 256
#define BN_EPS 1e-5f
#define NCHUNK 49            // ceil(N_NODES / 1024)
#define LOG2E 1.44269504f
#define FBLOCKS 4096
#define PROWS 64             // rows per proj2 block
#define PCH 32               // rows per staged chunk
#define PBLK 782             // ceil(N_NODES / PROWS)
#define FILLBLK 3125         // N_EDGES / 256
#define UBIAS 4.0f           // uniform logit bias: wt=exp2(u-4) keeps f16 accums in range

typedef _Float16 h2 __attribute__((ext_vector_type(2)));
typedef __fp16 fp16x2 __attribute__((ext_vector_type(2)));

__device__ __forceinline__ float dot2h(h2 a, h2 b, float c) {
#if __has_builtin(__builtin_amdgcn_fdot2)
    return __builtin_amdgcn_fdot2(a, b, c, false);
#else
    return c + (float)a.x * (float)b.x + (float)a.y * (float)b.y;
#endif
}

__device__ __forceinline__ h2 pkrtz(float lo, float hi) {
    fp16x2 r = __builtin_amdgcn_cvt_pkrtz(lo, hi);
    return __builtin_bit_cast(h2, r);
}

__device__ __forceinline__ unsigned int packh2(float lo, float hi) {
    return __builtin_bit_cast(unsigned int, pkrtz(lo, hi));
}

__device__ __forceinline__ h2 ash2(unsigned int u) {
    return __builtin_bit_cast(h2, u);
}

__device__ __forceinline__ h2 absh2(h2 v) {
    unsigned int u = __builtin_bit_cast(unsigned int, v) & 0x7FFF7FFFu;
    return __builtin_bit_cast(h2, u);
}

__device__ __forceinline__ float4 h4cvt(uint2 u) {
    h2 a = ash2(u.x);
    h2 b = ash2(u.y);
    return make_float4((float)a.x, (float)a.y, (float)b.x, (float)b.y);
}

// 16-lane (DPP row) rotate-add; after ror8,4,2,1 every lane holds its 16-group sum.
template <int CTRL>
__device__ __forceinline__ float ror_add(float x) {
    int y = __builtin_amdgcn_update_dpp(0, __float_as_int(x), CTRL, 0xF, 0xF, true);
    return x + __int_as_float(y);
}
__device__ __forceinline__ float row_reduce(float u) {
    u = ror_add<0x128>(u);
    u = ror_add<0x124>(u);
    u = ror_add<0x122>(u);
    u = ror_add<0x121>(u);
    return u;
}

__device__ __forceinline__ float fast_exp2(float x) {
    float r;
    asm("v_exp_f32 %0, %1" : "=v"(r) : "v"(x));
    return r;
}

// leaky_relu(z, 0.2) == 0.6*z + 0.4*|z| (f32 scalar, used in self-loop only)
__device__ __forceinline__ float lrelu(float z) {
    return fmaf(0.4f, fabsf(z), 0.6f * z);
}

// packed f16 leaky_relu over 2 channels
__device__ __forceinline__ h2 lrelu_pk(h2 z) {
    const h2 k06 = {(_Float16)0.6f, (_Float16)0.6f};
    const h2 k04 = {(_Float16)0.4f, (_Float16)0.4f};
    return z * k06 + absh2(z) * k04;
}

// ---------------- per-dst edge counts ----------------
__global__ void __launch_bounds__(256) cnt_kernel(const int* __restrict__ dst,
                                                  int* __restrict__ cnt) {
    int e = blockIdx.x * 256 + threadIdx.x;
    if (e < N_EDGES) atomicAdd(&cnt[dst[e]], 1);
}

// ---------------- scan A: per-chunk sums ----------------
__global__ void __launch_bounds__(256) scanA_kernel(const int* __restrict__ cnt,
                                                    int* __restrict__ part) {
    __shared__ int red[256];
    int b = blockIdx.x, tid = threadIdx.x;
    int base = b * 1024 + tid;
    int s = 0;
#pragma unroll
    for (int q = 0; q < 4; ++q) {
        int g = base + q * 256;
        s += (g < N_NODES) ? cnt[g] : 0;
    }
    red[tid] = s;
    __syncthreads();
    if (tid < 128) red[tid] += red[tid + 128];
    __syncthreads();
    if (tid < 64) {
        int v = red[tid] + red[tid + 64];
#pragma unroll
        for (int o = 32; o > 0; o >>= 1) v += __shfl_xor(v, o, 64);
        if (tid == 0) part[b] = v;
    }
}

// ---------------- scan C: per-chunk local scan; chunk base computed in-block ----------------
__global__ void scanC_kernel(const int* __restrict__ cnt, const int* __restrict__ part,
                             int* __restrict__ off) {
    __shared__ int wsum[16];
    __shared__ int base_s;
    int b = blockIdx.x, tid = threadIdx.x;
    int lane = tid & 63, w = tid >> 6;
    int i = b * 1024 + tid;
    int v = (i < N_NODES) ? cnt[i] : 0;
    int xv = v;
    for (int o = 1; o < 64; o <<= 1) {
        int t = __shfl_up(xv, o, 64);
        if (lane >= o) xv += t;
    }
    if (lane == 63) wsum[w] = xv;
    __syncthreads();
    if (tid < 64) {
        int pv = (tid < NCHUNK) ? part[tid] : 0;
        int px = pv;
        for (int o = 1; o < 64; o <<= 1) {
            int t = __shfl_up(px, o, 64);
            if (lane >= o) px += t;
        }
        if (tid == b) base_s = px - pv;
        int y = (tid < 16) ? wsum[tid] : 0;
        for (int o = 1; o < 16; o <<= 1) {
            int t = __shfl_up(y, o, 64);
            if (tid >= o) y += t;
        }
        if (tid < 16) wsum[tid] = y;
    }
    __syncthreads();
    int prefix = base_s + ((w > 0) ? wsum[w - 1] : 0);
    if (i < N_NODES) off[i + 1] = prefix + xv;
    if (b == 0 && tid == 0) off[0] = 0;
}

// ---------------- K4: proj2 (LDS row-broadcast GEMM, f32 in-staging cvt) UNION csr_fill ----
__global__ void __launch_bounds__(256) k4_kernel(const float* __restrict__ x,
                                                 const float* __restrict__ Wl,
                                                 const float* __restrict__ Wr,
                                                 unsigned short* __restrict__ xlh,
                                                 unsigned short* __restrict__ xrh,
                                                 const int* __restrict__ src,
                                                 const int* __restrict__ dst,
                                                 const float* __restrict__ ea,
                                                 const int* __restrict__ csr_off,
                                                 int* __restrict__ fill,
                                                 int* __restrict__ csr_src,
                                                 unsigned int* __restrict__ ea16) {
    __shared__ unsigned int lds[2][PCH * 32];
    int bid = blockIdx.x;
    int tid = threadIdx.x;

    if (bid >= PBLK) {
        // ---------------- csr_fill part ----------------
        int e = (bid - PBLK) * 256 + tid;
        if (e >= N_EDGES) return;
        int d = dst[e];
        int pos = csr_off[d] + atomicAdd(&fill[d], 1);
        csr_src[pos] = src[e];
        const float4* er = (const float4*)(ea + ((size_t)e << 4));
        float4 f0 = er[0], f1 = er[1], f2 = er[2], f3 = er[3];
        uint4 u0, u1;
        u0.x = packh2(f0.x, f0.y); u0.y = packh2(f0.z, f0.w);
        u0.z = packh2(f1.x, f1.y); u0.w = packh2(f1.z, f1.w);
        u1.x = packh2(f2.x, f2.y); u1.y = packh2(f2.z, f2.w);
        u1.z = packh2(f3.x, f3.y); u1.w = packh2(f3.z, f3.w);
        uint4* dp = (uint4*)(ea16 + ((size_t)pos << 3));
        dp[0] = u0;
        dp[1] = u1;
        return;
    }

    // ---------------- proj2 part ----------------
    int lane = tid & 63;
    int w = tid >> 6;
    int c0 = w * 128 + 2 * lane;              // first col of the pair
    const float* W = (c0 < HC) ? (Wl + c0) : (Wr + (c0 - HC));
    unsigned short* dp = (c0 < HC) ? (xlh + c0) : (xrh + (c0 - HC));

    h2 wa[32], wb[32];
#pragma unroll
    for (int m = 0; m < 32; ++m) {
        float2 lo = *(const float2*)(W + (size_t)(2 * m) * HC);
        float2 hi = *(const float2*)(W + (size_t)(2 * m + 1) * HC);
        wa[m] = pkrtz(lo.x, hi.x);
        wb[m] = pkrtz(lo.y, hi.y);
    }

    int row0 = bid * PROWS;
    if (row0 >= N_NODES) return;
    int nch = (N_NODES - row0 + PCH - 1) / PCH;
    if (nch > 2) nch = 2;

    auto GLOAD = [&](int base) -> uint4 {
        int r = base + (tid >> 3);
        if (r >= N_NODES) r = N_NODES - 1;
        const float4* xp = (const float4*)(x + ((size_t)r << 6)) + ((tid & 7) << 1);
        float4 a = xp[0], b = xp[1];
        uint4 u;
        u.x = packh2(a.x, a.y); u.y = packh2(a.z, a.w);
        u.z = packh2(b.x, b.y); u.w = packh2(b.z, b.w);
        return u;
    };

    uint4 reg = GLOAD(row0);
    for (int c = 0; c < nch; ++c) {
        ((uint4*)lds[c & 1])[tid] = reg;
        __syncthreads();
        if (c + 1 < nch) reg = GLOAD(row0 + (c + 1) * PCH);
        const unsigned int* L = lds[c & 1];
        int rbase = row0 + c * PCH;
        int rcnt = N_NODES - rbase;
        if (rcnt > PCH) rcnt = PCH;
        for (int r = 0; r < rcnt; ++r) {
            const uint4* rp = (const uint4*)(L + r * 32);
            float a0 = 0.f, a1 = 0.f;
#pragma unroll
            for (int q = 0; q < 8; ++q) {
                uint4 v = rp[q];
                a0 = dot2h(ash2(v.x), wa[4 * q + 0], a0);
                a1 = dot2h(ash2(v.x), wb[4 * q + 0], a1);
                a0 = dot2h(ash2(v.y), wa[4 * q + 1], a0);
                a1 = dot2h(ash2(v.y), wb[4 * q + 1], a1);
                a0 = dot2h(ash2(v.z), wa[4 * q + 2], a0);
                a1 = dot2h(ash2(v.z), wb[4 * q + 2], a1);
                a0 = dot2h(ash2(v.w), wa[4 * q + 3], a0);
                a1 = dot2h(ash2(v.w), wb[4 * q + 3], a1);
            }
            *(unsigned int*)(dp + (size_t)(rbase + r) * HC) = packh2(a0, a1);
        }
        __syncthreads();
    }
}

// ---------------- fused GATv2: one wave per node, packed-f16 stage, depth-3 prefetch ----
__global__ void __launch_bounds__(256) fused_kernel(const int* __restrict__ csr_off,
                                                    const int* __restrict__ csr_src,
                                                    const unsigned int* __restrict__ ea16,
                                                    const unsigned short* __restrict__ xlh,
                                                    const unsigned short* __restrict__ xrh,
                                                    const float* __restrict__ We,
                                                    const float* __restrict__ att,
                                                    const float* __restrict__ bias,
                                                    float* __restrict__ out) {
    int gtid = blockIdx.x * blockDim.x + threadIdx.x;
    int gw = gtid >> 6;
    int nw = (gridDim.x * blockDim.x) >> 6;
    int lane = threadIdx.x & 63;
    int c0 = lane & 15;
    int colbase = (lane >> 4) * C + c0 * 4;

    // per-lane W_e columns as packed f16 pairs
    h2 wh0[8], wh1[8], wh2[8], wh3[8];
#pragma unroll
    for (int k2 = 0; k2 < 8; ++k2) {
        float4 lo = *(const float4*)(We + (size_t)(2 * k2) * HC + colbase);
        float4 hi = *(const float4*)(We + (size_t)(2 * k2 + 1) * HC + colbase);
        wh0[k2].x = (_Float16)lo.x; wh0[k2].y = (_Float16)hi.x;
        wh1[k2].x = (_Float16)lo.y; wh1[k2].y = (_Float16)hi.y;
        wh2[k2].x = (_Float16)lo.z; wh2[k2].y = (_Float16)hi.z;
        wh3[k2].x = (_Float16)lo.w; wh3[k2].y = (_Float16)hi.w;
    }
    float4 av = *(const float4*)(att + colbase);
    av.x *= LOG2E; av.y *= LOG2E; av.z *= LOG2E; av.w *= LOG2E;   // log2 domain
    h2 attp01 = pkrtz(av.x, av.y);
    h2 attp23 = pkrtz(av.z, av.w);
    float4 bv = *(const float4*)(bias + c0 * 4);                  // loop-invariant

    // 32 dot2 accumulating the ee chunk for one edge (ea pair ua, ub)
    auto dot8 = [&](uint4 ua, uint4 ub, float& e0, float& e1, float& e2, float& e3) {
        h2 q;
        q = ash2(ua.x);
        e0 = dot2h(q, wh0[0], e0); e1 = dot2h(q, wh1[0], e1);
        e2 = dot2h(q, wh2[0], e2); e3 = dot2h(q, wh3[0], e3);
        q = ash2(ua.y);
        e0 = dot2h(q, wh0[1], e0); e1 = dot2h(q, wh1[1], e1);
        e2 = dot2h(q, wh2[1], e2); e3 = dot2h(q, wh3[1], e3);
        q = ash2(ua.z);
        e0 = dot2h(q, wh0[2], e0); e1 = dot2h(q, wh1[2], e1);
        e2 = dot2h(q, wh2[2], e2); e3 = dot2h(q, wh3[2], e3);
        q = ash2(ua.w);
        e0 = dot2h(q, wh0[3], e0); e1 = dot2h(q, wh1[3], e1);
        e2 = dot2h(q, wh2[3], e2); e3 = dot2h(q, wh3[3], e3);
        q = ash2(ub.x);
        e0 = dot2h(q, wh0[4], e0); e1 = dot2h(q, wh1[4], e1);
        e2 = dot2h(q, wh2[4], e2); e3 = dot2h(q, wh3[4], e3);
        q = ash2(ub.y);
        e0 = dot2h(q, wh0[5], e0); e1 = dot2h(q, wh1[5], e1);
        e2 = dot2h(q, wh2[5], e2); e3 = dot2h(q, wh3[5], e3);
        q = ash2(ub.z);
        e0 = dot2h(q, wh0[6], e0); e1 = dot2h(q, wh1[6], e1);
        e2 = dot2h(q, wh2[6], e2); e3 = dot2h(q, wh3[6], e3);
        q = ash2(ub.w);
        e0 = dot2h(q, wh0[7], e0); e1 = dot2h(q, wh1[7], e1);
        e2 = dot2h(q, wh2[7], e2); e3 = dot2h(q, wh3[7], e3);
    };

    for (int iv = gw; iv < N_NODES; iv += nw) {
        int i = __builtin_amdgcn_readfirstlane(iv);
        int off = __builtin_amdgcn_readfirstlane(csr_off[i]);
        int deg = __builtin_amdgcn_readfirstlane(csr_off[i + 1]) - off;
        const int* ps = csr_src + off;
        const uint4* pe = (const uint4*)(ea16 + ((size_t)off << 3));

        uint2 xrtu = *(const uint2*)(xrh + ((size_t)i << 8) + colbase);
        h2 xrtp0 = ash2(xrtu.x);
        h2 xrtp1 = ash2(xrtu.y);

        float den = 0.f;
        h2 ap0 = {(_Float16)0.f, (_Float16)0.f};     // packed f16 aggregation (4 ch)
        h2 ap1 = ap0;
        float s0 = 0.f, s1 = 0.f, s2 = 0.f, s3 = 0.f;

        // depth-3 gather prefetch (indices scalar; bases in SGPR)
        uint2 g0 = make_uint2(0, 0), g1 = g0, g2 = g0;
        if (deg > 0) {
            int t0 = __builtin_amdgcn_readfirstlane(ps[0]);
            g0 = *(const uint2*)(xlh + ((size_t)t0 << 8) + colbase);
            int t1 = __builtin_amdgcn_readfirstlane(ps[(deg > 1) ? 1 : 0]);
            g1 = *(const uint2*)(xlh + ((size_t)t1 << 8) + colbase);
            int t2 = __builtin_amdgcn_readfirstlane(ps[(deg > 2) ? 2 : 0]);
            g2 = *(const uint2*)(xlh + ((size_t)t2 << 8) + colbase);
        }

        for (int j = 0; j < deg; ++j) {
            int jn = (j + 3 < deg) ? (j + 3) : (deg - 1);
            int tn = __builtin_amdgcn_readfirstlane(ps[jn]);
            uint2 g3 = *(const uint2*)(xlh + ((size_t)tn << 8) + colbase);
            uint4 eA = pe[2 * j];
            uint4 eB = pe[2 * j + 1];

            float e0 = 0.f, e1 = 0.f, e2 = 0.f, e3 = 0.f;
            dot8(eA, eB, e0, e1, e2, e3);
            s0 += e0; s1 += e1; s2 += e2; s3 += e3;

            // packed z / lrelu / att-dot (4 channels as 2×h2)
            h2 xs0 = ash2(g0.x);
            h2 xs1 = ash2(g0.y);
            h2 z0 = pkrtz(e0, e1) + xs0 + xrtp0;
            h2 z1 = pkrtz(e2, e3) + xs1 + xrtp1;
            float u = dot2h(lrelu_pk(z0), attp01, 0.f);
            u = dot2h(lrelu_pk(z1), attp23, u);
            u = row_reduce(u);

            float wt = fast_exp2(u - UBIAS);
            den += wt;
            h2 wtp = pkrtz(wt, wt);
            ap0 = xs0 * wtp + ap0;
            ap1 = xs1 * wtp + ap1;

            g0 = g1; g1 = g2; g2 = g3;
        }

        // ---- self loop: ee_self = mean(ee_j) by linearity (f32 path, once) ----
        uint2 xliu = *(const uint2*)(xlh + ((size_t)i << 8) + colbase);
        float4 xli = h4cvt(xliu);
        float4 xrt = h4cvt(xrtu);
        float dninv = 1.f / fmaxf((float)deg, 1.f);
        {
            float z0 = fmaf(s0, dninv, xli.x + xrt.x);
            float z1 = fmaf(s1, dninv, xli.y + xrt.y);
            float z2 = fmaf(s2, dninv, xli.z + xrt.z);
            float z3 = fmaf(s3, dninv, xli.w + xrt.w);
            float u = lrelu(z0) * av.x;
            u = fmaf(lrelu(z1), av.y, u);
            u = fmaf(lrelu(z2), av.z, u);
            u = fmaf(lrelu(z3), av.w, u);
            u = row_reduce(u);
            float wt = fast_exp2(u - UBIAS);
            den += wt;
            h2 wtp = pkrtz(wt, wt);
            ap0 = ash2(xliu.x) * wtp + ap0;
            ap1 = ash2(xliu.y) * wtp + ap1;
        }

        // ---- normalize, head mean, bias, store ----
        float inv = 1.f / den;
        float r0 = (float)ap0.x * inv, r1 = (float)ap0.y * inv;
        float r2 = (float)ap1.x * inv, r3 = (float)ap1.y * inv;
        r0 += __shfl_xor(r0, 16); r0 += __shfl_xor(r0, 32);
        r1 += __shfl_xor(r1, 16); r1 += __shfl_xor(r1, 32);
        r2 += __shfl_xor(r2, 16); r2 += __shfl_xor(r2, 32);
        r3 += __shfl_xor(r3, 16); r3 += __shfl_xor(r3, 32);
        if (lane < 16) {
            float4 o;
            o.x = fmaf(r0, 0.25f, bv.x);
            o.y = fmaf(r1, 0.25f, bv.y);
            o.z = fmaf(r2, 0.25f, bv.z);
            o.w = fmaf(r3, 0.25f, bv.w);
            *(float4*)(out + (size_t)i * C + c0 * 4) = o;
        }
    }
}

// ---------------- BN statistics (sum, sumsq per channel) ----------------
__global__ void __launch_bounds__(256) bn_stats_kernel(const float* __restrict__ out,
                                                       float* __restrict__ bn) {
    int tid = threadIdx.x;
    int c = tid & 63;
    int r0 = blockIdx.x * 256 + (tid >> 6);
    int rend = (blockIdx.x * 256 + 256 < N_NODES) ? blockIdx.x * 256 + 256 : N_NODES;
    float s = 0.f, s2 = 0.f;
    for (int r = r0; r < rend; r += 4) {
        float v = out[(size_t)r * C + c];
        s += v; s2 += v * v;
    }
    __shared__ float red[256], red2[256];
    red[tid] = s; red2[tid] = s2;
    __syncthreads();
    if (tid < 128) { red[tid] += red[tid + 128]; red2[tid] += red2[tid + 128]; }
    __syncthreads();
    if (tid < 64) {
        atomicAdd(&bn[c], red[tid] + red[tid + 64]);
        atomicAdd(&bn[64 + c], red2[tid] + red2[tid + 64]);
    }
}

// ---------------- BN normalize + residual + ReLU (in place on out) ----------------
__global__ void __launch_bounds__(256) final_kernel(const float* __restrict__ x,
                                                    const float* __restrict__ bn,
                                                    const float* __restrict__ gamma,
                                                    const float* __restrict__ beta,
                                                    float* __restrict__ out) {
    int idx = blockIdx.x * 256 + threadIdx.x;
    if (idx >= N_NODES * C) return;
    int c = idx & 63;
    float mu = bn[c] * (1.f / N_NODES);
    float var = bn[64 + c] * (1.f / N_NODES) - mu * mu;
    float o = out[idx];
    float y = gamma[c] * (o - mu) * rsqrtf(var + BN_EPS) + beta[c] + x[idx];
    out[idx] = fmaxf(y, 0.f);
}

extern "C" void kernel_launch(void* const* d_in, const int* in_sizes, int n_in,
                              void* d_out, int out_size, void* d_ws, size_t ws_size,
                              hipStream_t stream) {
    const float* x     = (const float*)d_in[0];
    const int*   ei    = (const int*)d_in[1];
    const float* ea    = (const float*)d_in[2];
    const float* W_l   = (const float*)d_in[3];
    const float* W_r   = (const float*)d_in[4];
    const float* W_e   = (const float*)d_in[5];
    const float* att   = (const float*)d_in[6];
    const float* bias  = (const float*)d_in[7];
    const float* gamma = (const float*)d_in[8];
    const float* beta  = (const float*)d_in[9];
    float* out = (float*)d_out;

    const int* src = ei;
    const int* dst = ei + N_EDGES;

    char* p = (char*)d_ws;
    float*          bn      = (float*)p;          p += 512;
    int*            cnt     = (int*)p;            p += (size_t)N_NODES * 4;
    int*            fill    = (int*)p;            p += (size_t)N_NODES * 4;
    int*            csr_off = (int*)p;            p += (size_t)(N_NODES + 4) * 4;
    int*            part    = (int*)p;            p += 256;
    int*            csr_src = (int*)p;            p += (size_t)N_EDGES * 4;
    unsigned int*   ea16    = (unsigned int*)p;   p += (size_t)N_EDGES * 32;
    unsigned short* xlh     = (unsigned short*)p; p += (size_t)N_NODES * HC * 2;
    unsigned short* xrh     = (unsigned short*)p; p += (size_t)N_NODES * HC * 2;

    // zero bn + cnt + fill (contiguous)
    hipMemsetAsync(bn, 0, 512 + 2 * (size_t)N_NODES * 4, stream);

    cnt_kernel<<<FILLBLK, 256, 0, stream>>>(dst, cnt);
    scanA_kernel<<<NCHUNK, 256, 0, stream>>>(cnt, part);
    scanC_kernel<<<NCHUNK, 1024, 0, stream>>>(cnt, part, csr_off);
    k4_kernel<<<PBLK + FILLBLK, 256, 0, stream>>>(x, W_l, W_r, xlh, xrh,
                                                  src, dst, ea, csr_off, fill,
                                                  csr_src, ea16);
    fused_kernel<<<FBLOCKS, 256, 0, stream>>>(csr_off, csr_src, ea16, xlh, xrh, W_e,
                                              att, bias, out);
    bn_stats_kernel<<<(N_NODES + 255) / 256, 256, 0, stream>>>(out, bn);
    final_kernel<<<(N_NODES * C) / 256, 256, 0, stream>>>(x, bn, gamma, beta, out);
}